// Round 1
// baseline (131.452 us; speedup 1.0000x reference)
//
#include <hip/hip_runtime.h>

#define K    2048
#define E    64      // experts
#define TPB  64      // tokens per block
#define KC   64      // k-chunk

// W[64][2048] -> WT[2048][64]
__global__ __launch_bounds__(256) void transpose_w_kernel(const float* __restrict__ W,
                                                          float* __restrict__ WT) {
    int idx = blockIdx.x * blockDim.x + threadIdx.x;   // 0..131071
    int k = idx >> 6;
    int e = idx & 63;
    WT[idx] = W[e * K + k];
}

__global__ __launch_bounds__(256) void router_kernel(const float* __restrict__ x,
                                                     const float* __restrict__ WT,
                                                     float* __restrict__ out_w,
                                                     float* __restrict__ out_i,
                                                     int n_tokens) {
    __shared__ float xs[KC][TPB];     // [k][t]  16 KB
    __shared__ float ws[KC][E];       // [k][e]  16 KB
    __shared__ float ss[TPB][E + 1];  // padded scores for top-k

    const int tid = threadIdx.x;
    const int tb  = blockIdx.x * TPB;

    // compute-tile coords: 16 token-groups x 16 expert-groups, 4x4 per thread
    const int tg = tid >> 4;
    const int eg = tid & 15;
    const int t0 = tg * 4;
    const int e0 = eg * 4;

    // staging coords: token = tid&63, k-offset = (tid>>6)*16
    const int st  = tid & 63;
    const int skp = (tid >> 6) << 4;

    float acc[4][4] = {};

    const float* xrow = x + (size_t)(tb + st) * K + skp;
    float* wsf = &ws[0][0];

    for (int k0 = 0; k0 < K; k0 += KC) {
        // issue global loads first (previous chunk's compute may still be running)
        float4 xv[4];
        const float4* xsrc = reinterpret_cast<const float4*>(xrow + k0);
        #pragma unroll
        for (int j = 0; j < 4; ++j) xv[j] = xsrc[j];

        float4 wv[4];
        const float4* wsrc = reinterpret_cast<const float4*>(WT + (size_t)k0 * E);
        #pragma unroll
        for (int r = 0; r < 4; ++r) wv[r] = wsrc[r * 256 + tid];

        __syncthreads();   // previous chunk fully consumed

        // x transpose into LDS: banks = st%32 -> 2-way (free)
        #pragma unroll
        for (int j = 0; j < 4; ++j) {
            xs[skp + j * 4 + 0][st] = xv[j].x;
            xs[skp + j * 4 + 1][st] = xv[j].y;
            xs[skp + j * 4 + 2][st] = xv[j].z;
            xs[skp + j * 4 + 3][st] = xv[j].w;
        }
        // w chunk: straight contiguous copy, conflict-free b128 writes
        #pragma unroll
        for (int r = 0; r < 4; ++r)
            reinterpret_cast<float4*>(wsf)[r * 256 + tid] = wv[r];

        __syncthreads();

        #pragma unroll 4
        for (int k = 0; k < KC; ++k) {
            float4 x4 = *reinterpret_cast<const float4*>(&xs[k][t0]);
            float4 w4 = *reinterpret_cast<const float4*>(&ws[k][e0]);
            float xa[4] = {x4.x, x4.y, x4.z, x4.w};
            float wa[4] = {w4.x, w4.y, w4.z, w4.w};
            #pragma unroll
            for (int i = 0; i < 4; ++i)
                #pragma unroll
                for (int j = 0; j < 4; ++j)
                    acc[i][j] = fmaf(xa[i], wa[j], acc[i][j]);
        }
    }

    // scatter scores to LDS for per-token top-2
    #pragma unroll
    for (int i = 0; i < 4; ++i)
        #pragma unroll
        for (int j = 0; j < 4; ++j)
            ss[t0 + i][e0 + j] = acc[i][j];
    __syncthreads();

    if (tid < TPB) {
        const int t = tid;
        float m1 = -1e30f, m2 = -1e30f;
        int i1 = 0, i2 = 0;
        // strict '>' keeps the lower index on ties, matching jax.lax.top_k
        #pragma unroll
        for (int e = 0; e < E; ++e) {
            float v = ss[t][e];
            if (v > m1) { m2 = m1; i2 = i1; m1 = v; i1 = e; }
            else if (v > m2) { m2 = v; i2 = e; }
        }
        const int gt = tb + t;
        out_w[gt * 2 + 0] = m1;
        out_w[gt * 2 + 1] = m2;
        out_i[gt * 2 + 0] = (float)i1;   // indices chunk is read back as f32
        out_i[gt * 2 + 1] = (float)i2;
    }
}

extern "C" void kernel_launch(void* const* d_in, const int* in_sizes, int n_in,
                              void* d_out, int out_size, void* d_ws, size_t ws_size,
                              hipStream_t stream) {
    const float* x = (const float*)d_in[0];   // [16384, 2048] f32
    const float* W = (const float*)d_in[1];   // [64, 2048]   f32
    float* out = (float*)d_out;               // [16384*2 weights][16384*2 indices]

    const int n_tokens = in_sizes[0] / K;     // 16384
    float* WT = (float*)d_ws;                 // 2048*64*4 = 512 KB scratch

    hipLaunchKernelGGL(transpose_w_kernel, dim3((E * K) / 256), dim3(256), 0, stream, W, WT);
    hipLaunchKernelGGL(router_kernel, dim3(n_tokens / TPB), dim3(256), 0, stream,
                       x, WT, out, out + 2 * (size_t)n_tokens, n_tokens);
}

// Round 2
// 120.179 us; speedup vs baseline: 1.0938x; 1.0938x over previous
//
#include <hip/hip_runtime.h>
#include <stdint.h>

#define K     2048
#define E     64
#define TPB   32             // tokens per block
#define KC    64             // k-chunk
#define NC    (K / KC)       // 32 chunks
#define NTHR  128            // 2 waves

typedef float v2f __attribute__((ext_vector_type(2)));
typedef float v4f __attribute__((ext_vector_type(4)));

#define GLOBAL_AS __attribute__((address_space(1)))
#define LDS_AS    __attribute__((address_space(3)))

// W[64][2048] -> WT[2048][64]
__global__ __launch_bounds__(256) void transpose_w_kernel(const float* __restrict__ W,
                                                          float* __restrict__ WT) {
    int idx = blockIdx.x * blockDim.x + threadIdx.x;   // 0..131071
    int k = idx >> 6;
    int e = idx & 63;
    WT[idx] = W[e * K + k];
}

__global__ __launch_bounds__(NTHR) void router_kernel(const float* __restrict__ x,
                                                      const float* __restrict__ WT,
                                                      float* __restrict__ out_w,
                                                      float* __restrict__ out_i) {
    __shared__ float xs[2][KC][TPB];   // 2 x 8 KB
    __shared__ float ws[2][KC][E];     // 2 x 16 KB  (total 48 KB -> 3 blocks/CU)

    const int tid = threadIdx.x;
    const int tb  = blockIdx.x * TPB;

    // compute tile: 8 token-groups x 16 expert-groups, 4 tokens x 4 experts each
    const int t0 = (tid >> 4) * 4;
    const int e0 = (tid & 15) * 4;

    // staging coords: token = tid&31, k-offset = (tid>>5)*16
    const int st  = tid & 31;
    const int skp = (tid >> 5) << 4;

    const float* xrow = x + (size_t)(tb + st) * K + skp;

    v2f acc[4][2];
    #pragma unroll
    for (int i = 0; i < 4; ++i) {
        acc[i][0] = (v2f){0.0f, 0.0f};
        acc[i][1] = (v2f){0.0f, 0.0f};
    }

    float4 xv[4];

    // ---- prologue: stage chunk 0 into buffer 0 ----
    {
        const float4* xsrc = reinterpret_cast<const float4*>(xrow);
        #pragma unroll
        for (int j = 0; j < 4; ++j) xv[j] = xsrc[j];

        #pragma unroll
        for (int r = 0; r < 8; ++r) {
            int off = (r * NTHR + tid) * 4;      // float index, 16 B per thread
            __builtin_amdgcn_global_load_lds(
                (const GLOBAL_AS uint32_t*)(WT + off),
                (LDS_AS uint32_t*)(&ws[0][0][0] + off),
                16, 0, 0);
        }
        #pragma unroll
        for (int j = 0; j < 4; ++j) {
            xs[0][skp + j * 4 + 0][st] = xv[j].x;
            xs[0][skp + j * 4 + 1][st] = xv[j].y;
            xs[0][skp + j * 4 + 2][st] = xv[j].z;
            xs[0][skp + j * 4 + 3][st] = xv[j].w;
        }
        __syncthreads();   // compiler drains vmcnt(0) here -> gll complete
    }

    // ---- main loop: one barrier per chunk, loads for c+1 in flight during compute of c ----
    for (int c = 0; c < NC; ++c) {
        const int cur = c & 1;
        const int nxt = cur ^ 1;

        if (c + 1 < NC) {
            // issue next x chunk into regs (latency hides under compute below)
            const float4* xsrc = reinterpret_cast<const float4*>(xrow + (c + 1) * KC);
            #pragma unroll
            for (int j = 0; j < 4; ++j) xv[j] = xsrc[j];
            // issue next W chunk straight into LDS (async, drained at the barrier)
            const float* wbase = WT + (size_t)(c + 1) * KC * E;
            #pragma unroll
            for (int r = 0; r < 8; ++r) {
                int off = (r * NTHR + tid) * 4;
                __builtin_amdgcn_global_load_lds(
                    (const GLOBAL_AS uint32_t*)(wbase + off),
                    (LDS_AS uint32_t*)(&ws[nxt][0][0] + off),
                    16, 0, 0);
            }
        }

        // compute chunk c
        #pragma unroll 16
        for (int k = 0; k < KC; ++k) {
            v4f x4 = *reinterpret_cast<const v4f*>(&xs[cur][k][t0]);
            v4f w4 = *reinterpret_cast<const v4f*>(&ws[cur][k][e0]);
            v2f wlo = {w4.x, w4.y};
            v2f whi = {w4.z, w4.w};
            #pragma unroll
            for (int i = 0; i < 4; ++i) {
                acc[i][0] += x4[i] * wlo;   // contracts to v_pk_fma_f32
                acc[i][1] += x4[i] * whi;
            }
        }

        // write next x chunk into the other buffer (safe: nobody reads it this iter)
        if (c + 1 < NC) {
            #pragma unroll
            for (int j = 0; j < 4; ++j) {
                xs[nxt][skp + j * 4 + 0][st] = xv[j].x;
                xs[nxt][skp + j * 4 + 1][st] = xv[j].y;
                xs[nxt][skp + j * 4 + 2][st] = xv[j].z;
                xs[nxt][skp + j * 4 + 3][st] = xv[j].w;
            }
        }
        __syncthreads();
    }

    // ---- epilogue: top-2 per token ----
    // reuse xs as padded score buffer [TPB][E+1] (8.3 KB <= 16 KB)
    float (*ss)[E + 1] = reinterpret_cast<float (*)[E + 1]>(&xs[0][0][0]);
    #pragma unroll
    for (int i = 0; i < 4; ++i) {
        ss[t0 + i][e0 + 0] = acc[i][0][0];
        ss[t0 + i][e0 + 1] = acc[i][0][1];
        ss[t0 + i][e0 + 2] = acc[i][1][0];
        ss[t0 + i][e0 + 3] = acc[i][1][1];
    }
    __syncthreads();

    if (tid < TPB) {
        const int t = tid;
        float m1 = -1e30f, m2 = -1e30f;
        int i1 = 0, i2 = 0;
        // strict '>' keeps the lower index on ties, matching jax.lax.top_k
        #pragma unroll
        for (int e = 0; e < E; ++e) {
            float v = ss[t][e];
            if (v > m1) { m2 = m1; i2 = i1; m1 = v; i1 = e; }
            else if (v > m2) { m2 = v; i2 = e; }
        }
        const int gt = tb + t;
        out_w[gt * 2 + 0] = m1;
        out_w[gt * 2 + 1] = m2;
        out_i[gt * 2 + 0] = (float)i1;
        out_i[gt * 2 + 1] = (float)i2;
    }
}

extern "C" void kernel_launch(void* const* d_in, const int* in_sizes, int n_in,
                              void* d_out, int out_size, void* d_ws, size_t ws_size,
                              hipStream_t stream) {
    const float* x = (const float*)d_in[0];   // [16384, 2048] f32
    const float* W = (const float*)d_in[1];   // [64, 2048]   f32
    float* out = (float*)d_out;               // [16384*2 weights][16384*2 indices]

    const int n_tokens = in_sizes[0] / K;     // 16384
    float* WT = (float*)d_ws;                 // 2048*64*4 = 512 KB scratch

    hipLaunchKernelGGL(transpose_w_kernel, dim3((E * K) / 256), dim3(256), 0, stream, W, WT);
    hipLaunchKernelGGL(router_kernel, dim3(n_tokens / TPB), dim3(NTHR), 0, stream,
                       x, WT, out, out + 2 * (size_t)n_tokens);
}

// Round 3
// 91.274 us; speedup vs baseline: 1.4402x; 1.3167x over previous
//
#include <hip/hip_runtime.h>
#include <stdint.h>

#define KD    2048
#define ED    64
#define TPB   16             // tokens per block (one wave)
#define KC    32             // k-chunk
#define NC    (KD / KC)      // 64 chunks
#define NTHR  64             // 1 wave per block -> NO barriers in the K-loop

typedef float v2f __attribute__((ext_vector_type(2)));
typedef float v4f __attribute__((ext_vector_type(4)));

// W[64][2048] -> WT[2048][64]
__global__ __launch_bounds__(256) void transpose_w_kernel(const float* __restrict__ W,
                                                          float* __restrict__ WT) {
    int idx = blockIdx.x * blockDim.x + threadIdx.x;   // 0..131071
    int k = idx >> 6;
    int e = idx & 63;
    WT[idx] = W[e * KD + k];
}

__global__ __launch_bounds__(NTHR) void router_kernel(const float* __restrict__ x,
                                                      const float* __restrict__ WT,
                                                      float* __restrict__ out_w,
                                                      float* __restrict__ out_i) {
    __shared__ __align__(16) float xs[2][KC][TPB];   // 2 x 2 KB
    __shared__ __align__(16) float ws[2][KC][ED];    // 2 x 8 KB   (20 KB total)

    const int tid = threadIdx.x;
    const int tb  = blockIdx.x * TPB;

    // compute tile: 4 token-groups x 16 expert-groups, 4 tok x 4 exp per thread
    const int t0 = (tid >> 4) * 4;
    const int e0 = (tid & 15) * 4;

    // staging coords
    const int st = tid & 15;         // token
    const int sq = tid >> 4;         // k-quad base (0..3); quads sq and sq+4

    const float* xrow = x + (size_t)(tb + st) * KD;

    v2f acc[4][2];
    #pragma unroll
    for (int i = 0; i < 4; ++i) { acc[i][0] = (v2f){0.f, 0.f}; acc[i][1] = (v2f){0.f, 0.f}; }

    float4 xr0, xr1;
    float4 wr[8];

    // ---- stage chunk 0 into buffer 0 ----
    {
        const float4* xsrc = reinterpret_cast<const float4*>(xrow);
        xr0 = xsrc[sq];
        xr1 = xsrc[sq + 4];
        const float4* wsrc = reinterpret_cast<const float4*>(WT);
        #pragma unroll
        for (int p = 0; p < 8; ++p) wr[p] = wsrc[p * 64 + tid];

        xs[0][sq * 4 + 0][st] = xr0.x;  xs[0][sq * 4 + 1][st] = xr0.y;
        xs[0][sq * 4 + 2][st] = xr0.z;  xs[0][sq * 4 + 3][st] = xr0.w;
        xs[0][(sq + 4) * 4 + 0][st] = xr1.x;  xs[0][(sq + 4) * 4 + 1][st] = xr1.y;
        xs[0][(sq + 4) * 4 + 2][st] = xr1.z;  xs[0][(sq + 4) * 4 + 3][st] = xr1.w;
        float4* wdst = reinterpret_cast<float4*>(&ws[0][0][0]);
        #pragma unroll
        for (int p = 0; p < 8; ++p) wdst[p * 64 + tid] = wr[p];
    }

    // ---- main loop: self-paced wave pipeline, zero barriers ----
    for (int c = 0; c < NC; ++c) {
        const int cur = c & 1;
        const int nxt = cur ^ 1;

        if (c + 1 < NC) {
            // issue next chunk's loads; latency hides under the compute below,
            // and the ds_writes after compute wait on precise per-register vmcnt
            const float4* xsrc = reinterpret_cast<const float4*>(xrow + (c + 1) * KC);
            xr0 = xsrc[sq];
            xr1 = xsrc[sq + 4];
            const float4* wsrc = reinterpret_cast<const float4*>(WT + (size_t)(c + 1) * KC * ED);
            #pragma unroll
            for (int p = 0; p < 8; ++p) wr[p] = wsrc[p * 64 + tid];
        }

        #pragma unroll
        for (int k = 0; k < KC; ++k) {
            v4f x4 = *reinterpret_cast<const v4f*>(&xs[cur][k][t0]);
            v4f w4 = *reinterpret_cast<const v4f*>(&ws[cur][k][e0]);
            v2f wlo = {w4.x, w4.y};
            v2f whi = {w4.z, w4.w};
            #pragma unroll
            for (int i = 0; i < 4; ++i) {
                v2f xi = {x4[i], x4[i]};
                acc[i][0] += xi * wlo;   // v_pk_fma_f32
                acc[i][1] += xi * whi;
            }
        }

        if (c + 1 < NC) {
            xs[nxt][sq * 4 + 0][st] = xr0.x;  xs[nxt][sq * 4 + 1][st] = xr0.y;
            xs[nxt][sq * 4 + 2][st] = xr0.z;  xs[nxt][sq * 4 + 3][st] = xr0.w;
            xs[nxt][(sq + 4) * 4 + 0][st] = xr1.x;  xs[nxt][(sq + 4) * 4 + 1][st] = xr1.y;
            xs[nxt][(sq + 4) * 4 + 2][st] = xr1.z;  xs[nxt][(sq + 4) * 4 + 3][st] = xr1.w;
            float4* wdst = reinterpret_cast<float4*>(&ws[nxt][0][0]);
            #pragma unroll
            for (int p = 0; p < 8; ++p) wdst[p * 64 + tid] = wr[p];
        }
    }

    // ---- epilogue: top-2 per token (overlay score buffer on ws[0]) ----
    float (*ss)[ED + 1] = reinterpret_cast<float (*)[ED + 1]>(&ws[0][0][0]);  // 16x65x4 = 4160 B
    #pragma unroll
    for (int i = 0; i < 4; ++i) {
        ss[t0 + i][e0 + 0] = acc[i][0][0];
        ss[t0 + i][e0 + 1] = acc[i][0][1];
        ss[t0 + i][e0 + 2] = acc[i][1][0];
        ss[t0 + i][e0 + 3] = acc[i][1][1];
    }
    __syncthreads();   // single wave: compiles to a waitcnt, cheap

    if (tid < TPB) {
        const int t = tid;
        float m1 = -1e30f, m2 = -1e30f;
        int i1 = 0, i2 = 0;
        // strict '>' keeps the lower index on ties, matching jax.lax.top_k
        #pragma unroll
        for (int e = 0; e < ED; ++e) {
            float v = ss[t][e];
            if (v > m1) { m2 = m1; i2 = i1; m1 = v; i1 = e; }
            else if (v > m2) { m2 = v; i2 = e; }
        }
        const int gt = tb + t;
        out_w[gt * 2 + 0] = m1;
        out_w[gt * 2 + 1] = m2;
        out_i[gt * 2 + 0] = (float)i1;
        out_i[gt * 2 + 1] = (float)i2;
    }
}

extern "C" void kernel_launch(void* const* d_in, const int* in_sizes, int n_in,
                              void* d_out, int out_size, void* d_ws, size_t ws_size,
                              hipStream_t stream) {
    const float* x = (const float*)d_in[0];   // [16384, 2048] f32
    const float* W = (const float*)d_in[1];   // [64, 2048]   f32
    float* out = (float*)d_out;               // [16384*2 weights][16384*2 indices]

    const int n_tokens = in_sizes[0] / KD;    // 16384
    float* WT = (float*)d_ws;                 // 2048*64*4 = 512 KB scratch

    hipLaunchKernelGGL(transpose_w_kernel, dim3((ED * KD) / 256), dim3(256), 0, stream, W, WT);
    hipLaunchKernelGGL(router_kernel, dim3(n_tokens / TPB), dim3(NTHR), 0, stream,
                       x, WT, out, out + 2 * (size_t)n_tokens);
}

// Round 5
// 43.299 us; speedup vs baseline: 3.0359x; 2.1080x over previous
//
#include <hip/hip_runtime.h>
#include <stdint.h>

#define KDIM 2048
#define NEXP 64
#define MT   64              // tokens per block
#define KC   32              // k per chunk (one MFMA-K)
#define NCH  (KDIM / KC)     // 64 chunks
#define NTHR 256             // 4 waves

typedef _Float16 half8 __attribute__((ext_vector_type(8)));
typedef __fp16  fp16x2 __attribute__((ext_vector_type(2)));
typedef float f32x4 __attribute__((ext_vector_type(4)));

// W[64][2048] f32 -> Wh/Wl [64][2048] f16 (scaled by 256, hi/lo split)
__global__ __launch_bounds__(256) void prep_w(const float* __restrict__ W,
                                              _Float16* __restrict__ Wh,
                                              _Float16* __restrict__ Wl) {
    int idx = blockIdx.x * 256 + threadIdx.x;   // 131072 total
    float y = W[idx] * 256.0f;
    _Float16 h = (_Float16)y;
    _Float16 l = (_Float16)(y - (float)h);
    Wh[idx] = h;
    Wl[idx] = l;
}

// swizzled byte offset within one [64 rows][64B] LDS tensor
__device__ __forceinline__ int swz(int row, int byte_in_row) {
    return ((row << 6) + byte_in_row) ^ ((row & 14) << 3);
}

__device__ __forceinline__ uint32_t pkrtz(float a, float b) {
    fp16x2 h = __builtin_amdgcn_cvt_pkrtz(a, b);
    return __builtin_bit_cast(uint32_t, h);
}
__device__ __forceinline__ float lo_f(uint32_t u) {
    fp16x2 h = __builtin_bit_cast(fp16x2, u);
    return (float)h[0];
}
__device__ __forceinline__ float hi_f(uint32_t u) {
    fp16x2 h = __builtin_bit_cast(fp16x2, u);
    return (float)h[1];
}

__global__ __launch_bounds__(NTHR) void router_kernel(const float* __restrict__ x,
                                                      const _Float16* __restrict__ Wh,
                                                      const _Float16* __restrict__ Wl,
                                                      float* __restrict__ out_w,
                                                      float* __restrict__ out_i) {
    __shared__ char AsB[2][2][4096];   // [buf][h/l] x-tiles: 64 tok x 32 k f16
    __shared__ char BsB[2][2][4096];   // [buf][h/l] w-tiles: 64 exp x 32 k f16
    __shared__ float ss[MT][67];       // scores for top-2 (67: odd stride, 2-way banks)

    const int tid  = threadIdx.x;
    const int lane = tid & 63;
    const int wave = tid >> 6;
    const int wm   = wave >> 1;        // 2x2 wave grid: 32-tok x 32-exp per wave
    const int wn   = wave & 1;
    const int tb   = blockIdx.x * MT;

    // ---- staging coords ----
    // x: 2 slots: (row, seg) ; row in [0,64), seg in [0,8) of 16B f32 (=8B f16)
    const int xrow0 = tid >> 3;                 // 0..31
    const int xseg  = tid & 7;
    const float* xsrc0 = x + (size_t)(tb + xrow0) * KDIM + xseg * 4;
    const float* xsrc1 = x + (size_t)(tb + xrow0 + 32) * KDIM + xseg * 4;
    const int xoff0 = swz(xrow0, xseg * 8);
    const int xoff1 = swz(xrow0 + 32, xseg * 8);
    // w: 2 slots: same (rr,ss) from Wh and Wl; 16B f16 each
    const int wrr = tid >> 2;                   // 0..63 (expert)
    const int wss = tid & 3;                    // 16B segment of the 64B row-chunk
    const _Float16* wsrc0 = Wh + (size_t)wrr * KDIM + wss * 8;
    const _Float16* wsrc1 = Wl + (size_t)wrr * KDIM + wss * 8;
    const int woff = swz(wrr, wss * 16);

    // ---- compute-side read offsets (A and B symmetric: same lane->K mapping) ----
    const int kb = lane >> 4;                   // k-block 0..3
    const int ra0 = wm * 32 + (lane & 15);      // A rows for msub 0/1: ra0, ra0+16
    const int rb0 = wn * 32 + (lane & 15);      // B rows for nsub 0/1: rb0, rb0+16
    const int aoff0 = swz(ra0,      kb * 16);
    const int aoff1 = swz(ra0 + 16, kb * 16);
    const int boff0 = swz(rb0,      kb * 16);
    const int boff1 = swz(rb0 + 16, kb * 16);

    f32x4 acc[2][2];
    #pragma unroll
    for (int i = 0; i < 2; ++i)
        #pragma unroll
        for (int j = 0; j < 2; ++j)
            acc[i][j] = (f32x4){0.f, 0.f, 0.f, 0.f};

    float4 rx0, rx1;
    half8  rw0, rw1;

    auto LOAD = [&](int c) {
        rx0 = *reinterpret_cast<const float4*>(xsrc0 + c * KC);
        rx1 = *reinterpret_cast<const float4*>(xsrc1 + c * KC);
        rw0 = *reinterpret_cast<const half8*>(wsrc0 + c * KC);
        rw1 = *reinterpret_cast<const half8*>(wsrc1 + c * KC);
    };

    auto STORE = [&](int b) {
        // x: split each float4 into f16 hi/lo (x256 scaling; epilogue undoes by 2^-16)
        #pragma unroll
        for (int i = 0; i < 2; ++i) {
            float4 v = i ? rx1 : rx0;
            float y0 = v.x * 256.0f, y1 = v.y * 256.0f, y2 = v.z * 256.0f, y3 = v.w * 256.0f;
            uint32_t h01 = pkrtz(y0, y1);
            uint32_t h23 = pkrtz(y2, y3);
            float l0 = y0 - lo_f(h01), l1 = y1 - hi_f(h01);
            float l2 = y2 - lo_f(h23), l3 = y3 - hi_f(h23);
            uint32_t q01 = pkrtz(l0, l1);
            uint32_t q23 = pkrtz(l2, l3);
            uint2 hv, lv;
            hv.x = h01; hv.y = h23;
            lv.x = q01; lv.y = q23;
            int off = i ? xoff1 : xoff0;
            *reinterpret_cast<uint2*>(&AsB[b][0][0] + off) = hv;
            *reinterpret_cast<uint2*>(&AsB[b][1][0] + off) = lv;
        }
        *reinterpret_cast<half8*>(&BsB[b][0][0] + woff) = rw0;
        *reinterpret_cast<half8*>(&BsB[b][1][0] + woff) = rw1;
    };

    auto COMPUTE = [&](int b) {
        half8 ah[2], al[2], bh[2], bl[2];
        ah[0] = *reinterpret_cast<const half8*>(&AsB[b][0][0] + aoff0);
        ah[1] = *reinterpret_cast<const half8*>(&AsB[b][0][0] + aoff1);
        al[0] = *reinterpret_cast<const half8*>(&AsB[b][1][0] + aoff0);
        al[1] = *reinterpret_cast<const half8*>(&AsB[b][1][0] + aoff1);
        bh[0] = *reinterpret_cast<const half8*>(&BsB[b][0][0] + boff0);
        bh[1] = *reinterpret_cast<const half8*>(&BsB[b][0][0] + boff1);
        bl[0] = *reinterpret_cast<const half8*>(&BsB[b][1][0] + boff0);
        bl[1] = *reinterpret_cast<const half8*>(&BsB[b][1][0] + boff1);
        #pragma unroll
        for (int m = 0; m < 2; ++m)
            #pragma unroll
            for (int n = 0; n < 2; ++n) {
                acc[m][n] = __builtin_amdgcn_mfma_f32_16x16x32_f16(ah[m], bh[n], acc[m][n], 0, 0, 0);
                acc[m][n] = __builtin_amdgcn_mfma_f32_16x16x32_f16(al[m], bh[n], acc[m][n], 0, 0, 0);
                acc[m][n] = __builtin_amdgcn_mfma_f32_16x16x32_f16(ah[m], bl[n], acc[m][n], 0, 0, 0);
            }
    };

    // ---- pipeline: double-buffered LDS, 1-chunk register prefetch, 1 barrier/chunk ----
    LOAD(0);
    STORE(0);
    LOAD(1);
    __syncthreads();

    for (int c = 0; c < NCH; ++c) {
        const int p = c & 1;
        COMPUTE(p);
        if (c + 1 < NCH) {
            STORE(p ^ 1);                    // consumes regs of chunk c+1 (in flight ~1 chunk)
            if (c + 2 < NCH) LOAD(c + 2);    // issue next loads early
        }
        __syncthreads();
    }

    // ---- epilogue: scale back (exact 2^-16) and top-2 per token ----
    const float sc = 1.0f / 65536.0f;
    #pragma unroll
    for (int m = 0; m < 2; ++m)
        #pragma unroll
        for (int n = 0; n < 2; ++n)
            #pragma unroll
            for (int r = 0; r < 4; ++r) {
                int tok = wm * 32 + m * 16 + (lane >> 4) * 4 + r;   // C/D: row=(lane>>4)*4+reg
                int e   = wn * 32 + n * 16 + (lane & 15);           //      col=lane&15  (m89)
                ss[tok][e] = acc[m][n][r] * sc;
            }
    __syncthreads();

    if (tid < MT) {
        const int t = tid;
        float m1 = -1e30f, m2 = -1e30f;
        int i1 = 0, i2 = 0;
        // strict '>' keeps the lower index on ties, matching jax.lax.top_k
        #pragma unroll
        for (int e = 0; e < NEXP; ++e) {
            float v = ss[t][e];
            if (v > m1) { m2 = m1; i2 = i1; m1 = v; i1 = e; }
            else if (v > m2) { m2 = v; i2 = e; }
        }
        const int gt = tb + t;
        out_w[gt * 2 + 0] = m1;
        out_w[gt * 2 + 1] = m2;
        out_i[gt * 2 + 0] = (float)i1;
        out_i[gt * 2 + 1] = (float)i2;
    }
}

extern "C" void kernel_launch(void* const* d_in, const int* in_sizes, int n_in,
                              void* d_out, int out_size, void* d_ws, size_t ws_size,
                              hipStream_t stream) {
    const float* x = (const float*)d_in[0];   // [16384, 2048] f32
    const float* W = (const float*)d_in[1];   // [64, 2048]   f32
    float* out = (float*)d_out;               // [16384*2 weights][16384*2 indices]

    const int n_tokens = in_sizes[0] / KDIM;  // 16384
    _Float16* Whp = (_Float16*)d_ws;          // 256 KB
    _Float16* Wlp = Whp + (size_t)NEXP * KDIM; // +256 KB

    hipLaunchKernelGGL(prep_w, dim3((NEXP * KDIM) / 256), dim3(256), 0, stream, W, Whp, Wlp);
    hipLaunchKernelGGL(router_kernel, dim3(n_tokens / MT), dim3(NTHR), 0, stream,
                       x, Whp, Wlp, out, out + 2 * (size_t)n_tokens);
}